// Round 1
// baseline (974.829 us; speedup 1.0000x reference)
//
#include <hip/hip_runtime.h>

#define B_ 8
#define N_ 2048
#define K_ 30
#define H_ 128
#define LDA 136
#define EPS_ 1e-5f

typedef __attribute__((ext_vector_type(8))) short short8;
typedef __attribute__((ext_vector_type(4))) float f32x4;

__device__ inline unsigned short f2bf(float f) {
  union { float f; unsigned u; } v; v.f = f;
  unsigned r = v.u + 0x7fffu + ((v.u >> 16) & 1u);
  return (unsigned short)(r >> 16);
}

__device__ inline float gelu_f(float x) {
  return 0.5f * x * (1.0f + erff(x * 0.70710678118654752f));
}

// ---- wave-level 64x64 quadrant GEMM over one K=128 chunk ----
// A in LDS [128][LDA] bf16 rows; W is bf16 row-major [outDim][LDW] (B = W^T)
template<int LDW>
__device__ inline void wave_gemm(const unsigned short* __restrict__ sSrc,
                                 const unsigned short* __restrict__ W,
                                 int lane, int wr, int wcid, f32x4 (&acc)[4][4]) {
#pragma unroll
  for (int ks = 0; ks < 4; ++ks) {
    const int kk = ks * 32 + ((lane >> 4) << 3);
    short8 a[4];
#pragma unroll
    for (int m = 0; m < 4; ++m)
      a[m] = *(const short8*)(sSrc + (wr * 64 + m * 16 + (lane & 15)) * LDA + kk);
#pragma unroll
    for (int n = 0; n < 4; ++n) {
      const short8 bfr = *(const short8*)(W + (size_t)(wcid * 64 + n * 16 + (lane & 15)) * LDW + kk);
#pragma unroll
      for (int m = 0; m < 4; ++m)
        acc[m][n] = __builtin_amdgcn_mfma_f32_16x16x32_bf16(a[m], bfr, acc[m][n], 0, 0, 0);
    }
  }
}

__device__ inline void bias_gelu_store(const f32x4 (&acc)[4][4], const float* __restrict__ bias,
                                       unsigned short* __restrict__ dst, int lane, int wr, int wcid) {
#pragma unroll
  for (int n = 0; n < 4; ++n) {
    const int col = wcid * 64 + n * 16 + (lane & 15);
    const float bb = bias[col];
#pragma unroll
    for (int m = 0; m < 4; ++m) {
#pragma unroll
      for (int i = 0; i < 4; ++i) {
        const int row = wr * 64 + m * 16 + ((lane >> 4) << 2) + i;
        dst[row * LDA + col] = f2bf(gelu_f(acc[m][n][i] + bb));
      }
    }
  }
}

// ---- prep: convert all weight matrices fp32 -> bf16 into ws ----
__global__ __launch_bounds__(256) void prep(const float* __restrict__ w1, const float* __restrict__ w2,
                                            const float* __restrict__ w3, const float* __restrict__ w11,
                                            const float* __restrict__ w12, const float* __restrict__ w13,
                                            const float* __restrict__ din, const float* __restrict__ dout,
                                            unsigned short* __restrict__ dst) {
  const int i = blockIdx.x * 256 + threadIdx.x;  // grid covers exactly 294912
  const float* s; int off;
  if (i < 49152)       { s = w1;  off = 0; }
  else if (i < 65536)  { s = w2;  off = 49152; }
  else if (i < 81920)  { s = w3;  off = 65536; }
  else if (i < 131072) { s = w11; off = 81920; }
  else if (i < 147456) { s = w12; off = 131072; }
  else if (i < 163840) { s = w13; off = 147456; }
  else if (i < 229376) { s = din; off = 163840; }
  else                 { s = dout; off = 229376; }
  dst[i] = f2bf(s[i - off]);
}

// ---- k1: node message MLP + masked k-sum + LN1 -> hV1 (fp32 in ws) ----
__global__ __launch_bounds__(256) void k1(
    const float* __restrict__ hV, const float* __restrict__ hE,
    const int* __restrict__ Eidx, const float* __restrict__ mattend,
    const unsigned short* __restrict__ wc,
    const float* __restrict__ W1b, const float* __restrict__ W2b,
    const float* __restrict__ W3b, const float* __restrict__ n1g,
    const float* __restrict__ n1b, float* __restrict__ hV1) {
  __shared__ __align__(16) unsigned short sMem[2 * 128 * LDA];
  __shared__ float sRed[4][128];
  unsigned short* sA = sMem;
  unsigned short* sT = sMem + 128 * LDA;

  const int tid = threadIdx.x;
  const int lane = tid & 63;
  const int w = tid >> 6;
  const int wr = w >> 1, wcid = w & 1;
  const int v0 = blockIdx.x << 2;
  const int b = v0 >> 11;          // / N_
  const int n0 = v0 & (N_ - 1);

  const unsigned short* W1c = wc;          // [128][384]
  const unsigned short* W2c = wc + 49152;  // [128][128]
  const unsigned short* W3c = wc + 65536;  // [128][128]

  f32x4 acc[4][4];
  const f32x4 fz = {0.f, 0.f, 0.f, 0.f};
#pragma unroll
  for (int m = 0; m < 4; ++m)
#pragma unroll
    for (int n = 0; n < 4; ++n) acc[m][n] = fz;

  // GEMM1: 3 K-chunks (center hV | gathered hV | hE)
  for (int c = 0; c < 3; ++c) {
    for (int t = tid; t < 4096; t += 256) {
      const int r = t >> 5;
      const int col = (t & 31) << 2;
      const int g = r >> 5, kk = r & 31;
      float4 val = make_float4(0.f, 0.f, 0.f, 0.f);
      if (kk < K_) {
        const float* src;
        if (c == 0) {
          src = hV + (((size_t)(b * N_ + n0 + g)) << 7);
        } else if (c == 1) {
          const int j = Eidx[(b * N_ + n0 + g) * K_ + kk];
          src = hV + (((size_t)(b * N_ + j)) << 7);
        } else {
          src = hE + (((size_t)((b * N_ + n0 + g) * K_ + kk)) << 7);
        }
        val = *(const float4*)(src + col);
      }
      ushort4 o;
      o.x = f2bf(val.x); o.y = f2bf(val.y); o.z = f2bf(val.z); o.w = f2bf(val.w);
      *(ushort4*)(sA + r * LDA + col) = o;
    }
    __syncthreads();
    wave_gemm<384>(sA, W1c + c * 128, lane, wr, wcid, acc);
    __syncthreads();
  }
  bias_gelu_store(acc, W1b, sT, lane, wr, wcid);
  __syncthreads();

  f32x4 acc2[4][4];
#pragma unroll
  for (int m = 0; m < 4; ++m)
#pragma unroll
    for (int n = 0; n < 4; ++n) acc2[m][n] = fz;
  wave_gemm<128>(sT, W2c, lane, wr, wcid, acc2);
  bias_gelu_store(acc2, W2b, sA, lane, wr, wcid);
  __syncthreads();

  f32x4 acc3[4][4];
#pragma unroll
  for (int m = 0; m < 4; ++m)
#pragma unroll
    for (int n = 0; n < 4; ++n) acc3[m][n] = fz;
  wave_gemm<128>(sA, W3c, lane, wr, wcid, acc3);

  // bias + mask + sum over k (rows) -> sRed[group][col]
#pragma unroll
  for (int mp = 0; mp < 2; ++mp) {
    const int g = wr * 2 + mp;
    float mk[2][4];
#pragma unroll
    for (int mh = 0; mh < 2; ++mh)
#pragma unroll
      for (int i = 0; i < 4; ++i) {
        const int kk = mh * 16 + ((lane >> 4) << 2) + i;
        mk[mh][i] = (kk < K_) ? mattend[(b * N_ + n0 + g) * K_ + kk] : 0.f;
      }
#pragma unroll
    for (int n = 0; n < 4; ++n) {
      const int col = wcid * 64 + n * 16 + (lane & 15);
      const float bb = W3b[col];
      float s = 0.f;
#pragma unroll
      for (int mh = 0; mh < 2; ++mh)
#pragma unroll
        for (int i = 0; i < 4; ++i)
          s += (acc3[mp * 2 + mh][n][i] + bb) * mk[mh][i];
      s += __shfl_xor(s, 16);
      s += __shfl_xor(s, 32);
      if (lane < 16) sRed[g][col] = s;
    }
  }
  __syncthreads();

  // residual + LN1, one wave per node
  {
    const int g = w;
    const size_t base = ((size_t)(b * N_ + n0 + g)) << 7;
    const float x0 = hV[base + lane] + sRed[g][lane] * (1.0f / 30.0f);
    const float x1 = hV[base + 64 + lane] + sRed[g][64 + lane] * (1.0f / 30.0f);
    float s = x0 + x1;
#pragma unroll
    for (int o = 1; o < 64; o <<= 1) s += __shfl_xor(s, o);
    const float mean = s * (1.0f / 128.0f);
    const float d0 = x0 - mean, d1 = x1 - mean;
    float vs = d0 * d0 + d1 * d1;
#pragma unroll
    for (int o = 1; o < 64; o <<= 1) vs += __shfl_xor(vs, o);
    const float inv = rsqrtf(vs * (1.0f / 128.0f) + EPS_);
    hV1[base + lane] = n1g[lane] * (d0 * inv) + n1b[lane];
    hV1[base + 64 + lane] = n1g[64 + lane] * (d1 * inv) + n1b[64 + lane];
  }
}

// ---- k2: FFN + LN2 + mask_V -> outV (d_out) and hV2 bf16 (ws) ----
__global__ __launch_bounds__(256) void k2(
    const float* __restrict__ hV1, const unsigned short* __restrict__ wc,
    const float* __restrict__ dinb, const float* __restrict__ doutb,
    const float* __restrict__ n2g, const float* __restrict__ n2b,
    const float* __restrict__ maskV, float* __restrict__ outV,
    unsigned short* __restrict__ hV2c) {
  __shared__ __align__(16) unsigned short sMem[2 * 128 * LDA];
  unsigned short* sA = sMem;
  unsigned short* sT = sMem + 128 * LDA;

  const int tid = threadIdx.x;
  const int lane = tid & 63;
  const int w = tid >> 6;
  const int wr = w >> 1, wcid = w & 1;
  const int rowbase = blockIdx.x << 7;

  const unsigned short* dinc = wc + 163840;   // [512][128]
  const unsigned short* doutc = wc + 229376;  // [128][512]

  for (int t = tid; t < 4096; t += 256) {
    const int r = t >> 5;
    const int col = (t & 31) << 2;
    const float4 val = *(const float4*)(hV1 + (((size_t)(rowbase + r)) << 7) + col);
    ushort4 o;
    o.x = f2bf(val.x); o.y = f2bf(val.y); o.z = f2bf(val.z); o.w = f2bf(val.w);
    *(ushort4*)(sA + r * LDA + col) = o;
  }
  __syncthreads();

  const f32x4 fz = {0.f, 0.f, 0.f, 0.f};
  f32x4 acc2[4][4];
#pragma unroll
  for (int m = 0; m < 4; ++m)
#pragma unroll
    for (int n = 0; n < 4; ++n) acc2[m][n] = fz;

  for (int c = 0; c < 4; ++c) {
    f32x4 acc1[4][4];
#pragma unroll
    for (int m = 0; m < 4; ++m)
#pragma unroll
      for (int n = 0; n < 4; ++n) acc1[m][n] = fz;
    wave_gemm<128>(sA, dinc + (size_t)c * 128 * 128, lane, wr, wcid, acc1);
    __syncthreads();  // previous chunk's GEMM2 reads of sT done
    bias_gelu_store(acc1, dinb + c * 128, sT, lane, wr, wcid);
    __syncthreads();
    wave_gemm<512>(sT, doutc + c * 128, lane, wr, wcid, acc2);
  }
  __syncthreads();

  float* sX = (float*)sMem;  // alias; GEMM reads are done
#pragma unroll
  for (int n = 0; n < 4; ++n) {
    const int col = wcid * 64 + n * 16 + (lane & 15);
    const float bb = doutb[col];
#pragma unroll
    for (int m = 0; m < 4; ++m)
#pragma unroll
      for (int i = 0; i < 4; ++i) {
        const int row = wr * 64 + m * 16 + ((lane >> 4) << 2) + i;
        sX[row * 129 + col] = acc2[m][n][i] + bb + hV1[(((size_t)(rowbase + row)) << 7) + col];
      }
  }
  __syncthreads();

  if (tid < 128) {
    const int row = tid;
    const size_t gr = rowbase + row;
    float s = 0.f;
    for (int c = 0; c < 128; ++c) s += sX[row * 129 + c];
    const float mean = s * (1.0f / 128.0f);
    float vs = 0.f;
    for (int c = 0; c < 128; ++c) { const float d = sX[row * 129 + c] - mean; vs += d * d; }
    const float inv = rsqrtf(vs * (1.0f / 128.0f) + EPS_);
    const float mv = maskV[gr];
    for (int c = 0; c < 128; ++c) {
      const float y = (n2g[c] * ((sX[row * 129 + c] - mean) * inv) + n2b[c]) * mv;
      outV[(gr << 7) + c] = y;
      hV2c[(gr << 7) + c] = f2bf(y);
    }
  }
}

// ---- k3: edge message MLP + residual + LN3 -> outE ----
__global__ __launch_bounds__(256) void k3(
    const unsigned short* __restrict__ hV2c, const float* __restrict__ hE,
    const int* __restrict__ Eidx, const unsigned short* __restrict__ wc,
    const float* __restrict__ W11b, const float* __restrict__ W12b,
    const float* __restrict__ W13b, const float* __restrict__ n3g,
    const float* __restrict__ n3b, float* __restrict__ outE) {
  __shared__ __align__(16) unsigned short sMem[2 * 128 * LDA];
  unsigned short* sA = sMem;
  unsigned short* sT = sMem + 128 * LDA;

  const int tid = threadIdx.x;
  const int lane = tid & 63;
  const int w = tid >> 6;
  const int wr = w >> 1, wcid = w & 1;
  const int v0 = blockIdx.x << 2;
  const int b = v0 >> 11;
  const int n0 = v0 & (N_ - 1);

  const unsigned short* W11c = wc + 81920;
  const unsigned short* W12c = wc + 131072;
  const unsigned short* W13c = wc + 147456;

  const f32x4 fz = {0.f, 0.f, 0.f, 0.f};
  f32x4 acc[4][4];
#pragma unroll
  for (int m = 0; m < 4; ++m)
#pragma unroll
    for (int n = 0; n < 4; ++n) acc[m][n] = fz;

  for (int c = 0; c < 3; ++c) {
    for (int t = tid; t < 4096; t += 256) {
      const int r = t >> 5;
      const int col = (t & 31) << 2;
      const int g = r >> 5, kk = r & 31;
      if (c < 2) {
        ushort4 v = make_ushort4(0, 0, 0, 0);
        if (kk < K_) {
          const unsigned short* src;
          if (c == 0) {
            src = hV2c + (((size_t)(b * N_ + n0 + g)) << 7);
          } else {
            const int j = Eidx[(b * N_ + n0 + g) * K_ + kk];
            src = hV2c + (((size_t)(b * N_ + j)) << 7);
          }
          v = *(const ushort4*)(src + col);
        }
        *(ushort4*)(sA + r * LDA + col) = v;
      } else {
        float4 val = make_float4(0.f, 0.f, 0.f, 0.f);
        if (kk < K_)
          val = *(const float4*)(hE + (((size_t)((b * N_ + n0 + g) * K_ + kk)) << 7) + col);
        ushort4 o;
        o.x = f2bf(val.x); o.y = f2bf(val.y); o.z = f2bf(val.z); o.w = f2bf(val.w);
        *(ushort4*)(sA + r * LDA + col) = o;
      }
    }
    __syncthreads();
    wave_gemm<384>(sA, W11c + c * 128, lane, wr, wcid, acc);
    __syncthreads();
  }
  bias_gelu_store(acc, W11b, sT, lane, wr, wcid);
  __syncthreads();

  f32x4 acc2[4][4];
#pragma unroll
  for (int m = 0; m < 4; ++m)
#pragma unroll
    for (int n = 0; n < 4; ++n) acc2[m][n] = fz;
  wave_gemm<128>(sT, W12c, lane, wr, wcid, acc2);
  bias_gelu_store(acc2, W12b, sA, lane, wr, wcid);
  __syncthreads();

  f32x4 acc3[4][4];
#pragma unroll
  for (int m = 0; m < 4; ++m)
#pragma unroll
    for (int n = 0; n < 4; ++n) acc3[m][n] = fz;
  wave_gemm<128>(sA, W13c, lane, wr, wcid, acc3);
  __syncthreads();  // all LDS reads done before aliasing

  float* sX = (float*)sMem;
#pragma unroll
  for (int n = 0; n < 4; ++n) {
    const int col = wcid * 64 + n * 16 + (lane & 15);
    const float bb = W13b[col];
#pragma unroll
    for (int m = 0; m < 4; ++m)
#pragma unroll
      for (int i = 0; i < 4; ++i) {
        const int row = wr * 64 + m * 16 + ((lane >> 4) << 2) + i;
        const int g = row >> 5, kk = row & 31;
        float x = acc3[m][n][i] + bb;
        if (kk < K_)
          x += hE[(((size_t)((b * N_ + n0 + g) * K_ + kk)) << 7) + col];
        sX[row * 129 + col] = x;
      }
  }
  __syncthreads();

  if (tid < 128) {
    const int row = tid;
    const int g = row >> 5, kk = row & 31;
    if (kk < K_) {
      float s = 0.f;
      for (int c = 0; c < 128; ++c) s += sX[row * 129 + c];
      const float mean = s * (1.0f / 128.0f);
      float vs = 0.f;
      for (int c = 0; c < 128; ++c) { const float d = sX[row * 129 + c] - mean; vs += d * d; }
      const float inv = rsqrtf(vs * (1.0f / 128.0f) + EPS_);
      float* dst = outE + (((size_t)((b * N_ + n0 + g) * K_ + kk)) << 7);
      for (int c = 0; c < 128; ++c)
        dst[c] = n3g[c] * ((sX[row * 129 + c] - mean) * inv) + n3b[c];
    }
  }
}

extern "C" void kernel_launch(void* const* d_in, const int* in_sizes, int n_in,
                              void* d_out, int out_size, void* d_ws, size_t ws_size,
                              hipStream_t stream) {
  const float* hV = (const float*)d_in[0];
  const float* hE = (const float*)d_in[1];
  const int* Eidx = (const int*)d_in[2];
  const float* maskV = (const float*)d_in[3];
  const float* mattend = (const float*)d_in[4];
  const float* W1w = (const float*)d_in[5];   const float* W1b = (const float*)d_in[6];
  const float* W2w = (const float*)d_in[7];   const float* W2b = (const float*)d_in[8];
  const float* W3w = (const float*)d_in[9];   const float* W3b = (const float*)d_in[10];
  const float* W11w = (const float*)d_in[11]; const float* W11b = (const float*)d_in[12];
  const float* W12w = (const float*)d_in[13]; const float* W12b = (const float*)d_in[14];
  const float* W13w = (const float*)d_in[15]; const float* W13b = (const float*)d_in[16];
  const float* n1g = (const float*)d_in[17];  const float* n1b = (const float*)d_in[18];
  const float* n2g = (const float*)d_in[19];  const float* n2b = (const float*)d_in[20];
  const float* n3g = (const float*)d_in[21];  const float* n3b = (const float*)d_in[22];
  const float* dinw = (const float*)d_in[23]; const float* dinb = (const float*)d_in[24];
  const float* doutw = (const float*)d_in[25]; const float* doutb = (const float*)d_in[26];

  unsigned short* wc = (unsigned short*)d_ws;                       // 294912 bf16 weights
  float* hV1 = (float*)((char*)d_ws + 589824);                      // [B*N*H] fp32
  unsigned short* hV2c = (unsigned short*)((char*)d_ws + 589824 + 8388608);  // [B*N*H] bf16

  float* outV = (float*)d_out;
  float* outE = outV + (size_t)B_ * N_ * H_;

  prep<<<1152, 256, 0, stream>>>(W1w, W2w, W3w, W11w, W12w, W13w, dinw, doutw, wc);
  k1<<<4096, 256, 0, stream>>>(hV, hE, Eidx, mattend, wc, W1b, W2b, W3b, n1g, n1b, hV1);
  k2<<<128, 256, 0, stream>>>(hV1, wc, dinb, doutb, n2g, n2b, maskV, outV, hV2c);
  k3<<<4096, 256, 0, stream>>>(hV2c, hE, Eidx, wc, W11b, W12b, W13b, n3g, n3b, outE);
}

// Round 2
// 761.709 us; speedup vs baseline: 1.2798x; 1.2798x over previous
//
#include <hip/hip_runtime.h>

#define B_ 8
#define N_ 2048
#define K_ 30
#define H_ 128
#define LDA 136
#define EPS_ 1e-5f

typedef __attribute__((ext_vector_type(8))) short short8;
typedef __attribute__((ext_vector_type(4))) float f32x4;

__device__ inline unsigned short f2bf(float f) {
  union { float f; unsigned u; } v; v.f = f;
  unsigned r = v.u + 0x7fffu + ((v.u >> 16) & 1u);
  return (unsigned short)(r >> 16);
}

__device__ inline float bf2f(unsigned short h) {
  union { unsigned u; float f; } v; v.u = ((unsigned)h) << 16; return v.f;
}

__device__ inline float gelu_f(float x) {
  return 0.5f * x * (1.0f + erff(x * 0.70710678118654752f));
}

__device__ inline short8 pack8(float4 a, float4 b) {
  short8 o;
  o[0] = (short)f2bf(a.x); o[1] = (short)f2bf(a.y); o[2] = (short)f2bf(a.z); o[3] = (short)f2bf(a.w);
  o[4] = (short)f2bf(b.x); o[5] = (short)f2bf(b.y); o[6] = (short)f2bf(b.z); o[7] = (short)f2bf(b.w);
  return o;
}

// stage 128 rows x 128 bf16 cols into sA; rowptr(r) -> bf16 row base
template<typename F>
__device__ inline void stage_bf16(unsigned short* sA, int tid, F rowptr) {
  for (int t = tid; t < 2048; t += 256) {
    const int r = t >> 4, seg = t & 15;
    const unsigned short* src = rowptr(r) + seg * 8;
    *(short8*)(sA + r * LDA + seg * 8) = *(const short8*)src;
  }
}

// stage with fp32 -> bf16 convert; rowptr(r) -> f32 row base
template<typename F>
__device__ inline void stage_cvt(unsigned short* sA, int tid, F rowptr) {
  for (int t = tid; t < 2048; t += 256) {
    const int r = t >> 4, seg = t & 15;
    const float* src = rowptr(r) + seg * 8;
    const float4 v0 = *(const float4*)src;
    const float4 v1 = *(const float4*)(src + 4);
    *(short8*)(sA + r * LDA + seg * 8) = pack8(v0, v1);
  }
}

// ---- wave-level 64x64 quadrant GEMM over one K=128 chunk ----
template<int LDW>
__device__ inline void wave_gemm(const unsigned short* __restrict__ sSrc,
                                 const unsigned short* __restrict__ W,
                                 int lane, int wr, int wcid, f32x4 (&acc)[4][4]) {
#pragma unroll
  for (int ks = 0; ks < 4; ++ks) {
    const int kk = ks * 32 + ((lane >> 4) << 3);
    short8 a[4];
#pragma unroll
    for (int m = 0; m < 4; ++m)
      a[m] = *(const short8*)(sSrc + (wr * 64 + m * 16 + (lane & 15)) * LDA + kk);
#pragma unroll
    for (int n = 0; n < 4; ++n) {
      const short8 bfr = *(const short8*)(W + (size_t)(wcid * 64 + n * 16 + (lane & 15)) * LDW + kk);
#pragma unroll
      for (int m = 0; m < 4; ++m)
        acc[m][n] = __builtin_amdgcn_mfma_f32_16x16x32_bf16(a[m], bfr, acc[m][n], 0, 0, 0);
    }
  }
}

__device__ inline void bias_gelu_store(const f32x4 (&acc)[4][4], const float* __restrict__ bias,
                                       unsigned short* __restrict__ dst, int lane, int wr, int wcid) {
#pragma unroll
  for (int n = 0; n < 4; ++n) {
    const int col = wcid * 64 + n * 16 + (lane & 15);
    const float bb = bias[col];
#pragma unroll
    for (int m = 0; m < 4; ++m) {
#pragma unroll
      for (int i = 0; i < 4; ++i) {
        const int row = wr * 64 + m * 16 + ((lane >> 4) << 2) + i;
        dst[row * LDA + col] = f2bf(gelu_f(acc[m][n][i] + bb));
      }
    }
  }
}

#define ZERO_ACC(A) \
  _Pragma("unroll") for (int m_ = 0; m_ < 4; ++m_) \
  _Pragma("unroll") for (int n_ = 0; n_ < 4; ++n_) A[m_][n_] = (f32x4){0.f, 0.f, 0.f, 0.f};

// ---- prep: weights fp32 -> bf16 ----
__global__ __launch_bounds__(256) void prep(const float* __restrict__ w1, const float* __restrict__ w2,
                                            const float* __restrict__ w3, const float* __restrict__ w11,
                                            const float* __restrict__ w12, const float* __restrict__ w13,
                                            const float* __restrict__ din, const float* __restrict__ dout,
                                            unsigned short* __restrict__ dst) {
  const int i = blockIdx.x * 256 + threadIdx.x;  // grid covers exactly 294912
  const float* s; int off;
  if (i < 49152)       { s = w1;  off = 0; }
  else if (i < 65536)  { s = w2;  off = 49152; }
  else if (i < 81920)  { s = w3;  off = 65536; }
  else if (i < 131072) { s = w11; off = 81920; }
  else if (i < 147456) { s = w12; off = 131072; }
  else if (i < 163840) { s = w13; off = 147456; }
  else if (i < 229376) { s = din; off = 163840; }
  else                 { s = dout; off = 229376; }
  dst[i] = f2bf(s[i - off]);
}

// ---- cvt8: fp32 -> bf16, 8 elems/thread ----
__global__ __launch_bounds__(256) void cvt8(const float* __restrict__ src,
                                            unsigned short* __restrict__ dst, int n8) {
  const int i = blockIdx.x * 256 + threadIdx.x;
  if (i >= n8) return;
  const float4 a = ((const float4*)src)[i * 2];
  const float4 b = ((const float4*)src)[i * 2 + 1];
  ((short8*)dst)[i] = pack8(a, b);
}

// ---- k1: node message MLP + masked k-sum + LN1 -> hV1b (bf16); side-writes hEb ----
template<bool EBF>
__global__ __launch_bounds__(256, 4) void k1(
    const float* __restrict__ hV, const unsigned short* __restrict__ hVb,
    const float* __restrict__ hE, unsigned short* __restrict__ hEb,
    const int* __restrict__ Eidx, const float* __restrict__ mattend,
    const unsigned short* __restrict__ wc,
    const float* __restrict__ W1b, const float* __restrict__ W2b,
    const float* __restrict__ W3b, const float* __restrict__ n1g,
    const float* __restrict__ n1b, unsigned short* __restrict__ hV1b) {
  __shared__ __align__(16) unsigned short sA[128 * LDA];
  __shared__ float sRed[4][128];

  const int tid = threadIdx.x;
  const int lane = tid & 63;
  const int w = tid >> 6;
  const int wr = w >> 1, wcid = w & 1;
  const int v0 = blockIdx.x << 2;
  const int b = v0 >> 11;
  const int n0 = v0 & (N_ - 1);
  const int bBase = b * N_;

  const unsigned short* W1c = wc;          // [128][384]
  const unsigned short* W2c = wc + 49152;  // [128][128]
  const unsigned short* W3c = wc + 65536;  // [128][128]

  f32x4 acc[4][4];
  ZERO_ACC(acc)

  // chunk 0: center hV (bf16)
  stage_bf16(sA, tid, [&](int r) {
    const int g = r >> 5;
    return hVb + (((size_t)(bBase + n0 + g)) << 7);
  });
  __syncthreads();
  wave_gemm<384>(sA, W1c, lane, wr, wcid, acc);
  __syncthreads();

  // chunk 1: gathered hV (bf16)
  stage_bf16(sA, tid, [&](int r) {
    const int g = r >> 5;
    int kk = r & 31; if (kk >= K_) kk = K_ - 1;
    const int j = Eidx[(bBase + n0 + g) * K_ + kk];
    return hVb + (((size_t)(bBase + j)) << 7);
  });
  __syncthreads();
  wave_gemm<384>(sA, W1c + 128, lane, wr, wcid, acc);
  __syncthreads();

  // chunk 2: hE (fp32 -> bf16), side-write bf16 copy to hEb
  for (int t = tid; t < 2048; t += 256) {
    const int r = t >> 4, seg = t & 15;
    const int g = r >> 5;
    int kk = r & 31; const int kc = kk < K_ ? kk : K_ - 1;
    const size_t erow = ((size_t)((bBase + n0 + g) * K_ + kc)) << 7;
    const float* src = hE + erow + seg * 8;
    const short8 o = pack8(*(const float4*)src, *(const float4*)(src + 4));
    *(short8*)(sA + r * LDA + seg * 8) = o;
    if (EBF && kk < K_)
      *(short8*)(hEb + erow + seg * 8) = o;
  }
  __syncthreads();
  wave_gemm<384>(sA, W1c + 256, lane, wr, wcid, acc);
  __syncthreads();

  bias_gelu_store(acc, W1b, sA, lane, wr, wcid);
  __syncthreads();

  f32x4 acc2[4][4];
  ZERO_ACC(acc2)
  wave_gemm<128>(sA, W2c, lane, wr, wcid, acc2);
  __syncthreads();
  bias_gelu_store(acc2, W2b, sA, lane, wr, wcid);
  __syncthreads();

  f32x4 acc3[4][4];
  ZERO_ACC(acc3)
  wave_gemm<128>(sA, W3c, lane, wr, wcid, acc3);

  // bias + mask + sum over k rows -> sRed[node][col]
#pragma unroll
  for (int mp = 0; mp < 2; ++mp) {
    const int g = wr * 2 + mp;
    float mk[2][4];
#pragma unroll
    for (int mh = 0; mh < 2; ++mh)
#pragma unroll
      for (int i = 0; i < 4; ++i) {
        const int kk = mh * 16 + ((lane >> 4) << 2) + i;
        mk[mh][i] = (kk < K_) ? mattend[(bBase + n0 + g) * K_ + kk] : 0.f;
      }
#pragma unroll
    for (int n = 0; n < 4; ++n) {
      const int col = wcid * 64 + n * 16 + (lane & 15);
      const float bb = W3b[col];
      float s = 0.f;
#pragma unroll
      for (int mh = 0; mh < 2; ++mh)
#pragma unroll
        for (int i = 0; i < 4; ++i)
          s += (acc3[mp * 2 + mh][n][i] + bb) * mk[mh][i];
      s += __shfl_xor(s, 16);
      s += __shfl_xor(s, 32);
      if (lane < 16) sRed[g][col] = s;
    }
  }
  __syncthreads();

  // residual + LN1, one wave per node -> bf16
  {
    const int g = w;
    const size_t base = ((size_t)(bBase + n0 + g)) << 7;
    const float x0 = hV[base + lane] + sRed[g][lane] * (1.0f / 30.0f);
    const float x1 = hV[base + 64 + lane] + sRed[g][64 + lane] * (1.0f / 30.0f);
    float s = x0 + x1;
#pragma unroll
    for (int o = 1; o < 64; o <<= 1) s += __shfl_xor(s, o);
    const float mean = s * (1.0f / 128.0f);
    const float d0 = x0 - mean, d1 = x1 - mean;
    float vs = d0 * d0 + d1 * d1;
#pragma unroll
    for (int o = 1; o < 64; o <<= 1) vs += __shfl_xor(vs, o);
    const float inv = rsqrtf(vs * (1.0f / 128.0f) + EPS_);
    hV1b[base + lane] = f2bf(n1g[lane] * (d0 * inv) + n1b[lane]);
    hV1b[base + 64 + lane] = f2bf(n1g[64 + lane] * (d1 * inv) + n1b[64 + lane]);
  }
}

// ---- k2: FFN + LN2 + mask_V -> outV (fp32) and hV2c (bf16) ----
__global__ __launch_bounds__(256) void k2(
    const unsigned short* __restrict__ hV1b, const unsigned short* __restrict__ wc,
    const float* __restrict__ dinb, const float* __restrict__ doutb,
    const float* __restrict__ n2g, const float* __restrict__ n2b,
    const float* __restrict__ maskV, float* __restrict__ outV,
    unsigned short* __restrict__ hV2c) {
  __shared__ __align__(16) unsigned short sA[128 * LDA];
  __shared__ __align__(16) unsigned short sT[128 * LDA];
  __shared__ float sStat[128][2][2];

  const int tid = threadIdx.x;
  const int lane = tid & 63;
  const int w = tid >> 6;
  const int wr = w >> 1, wcid = w & 1;
  const int rowbase = blockIdx.x << 7;

  const unsigned short* dinc = wc + 163840;   // [512][128]
  const unsigned short* doutc = wc + 229376;  // [128][512]

  stage_bf16(sA, tid, [&](int r) { return hV1b + (((size_t)(rowbase + r)) << 7); });
  __syncthreads();

  f32x4 acc2[4][4];
  ZERO_ACC(acc2)

  for (int c = 0; c < 4; ++c) {
    f32x4 acc1[4][4];
    ZERO_ACC(acc1)
    wave_gemm<128>(sA, dinc + (size_t)c * 128 * 128, lane, wr, wcid, acc1);
    __syncthreads();  // previous chunk's GEMM2 reads of sT done
    bias_gelu_store(acc1, dinb + c * 128, sT, lane, wr, wcid);
    __syncthreads();
    wave_gemm<512>(sT, doutc + c * 128, lane, wr, wcid, acc2);
  }

  // register epilogue: x = acc2 + bias + residual; LN2 stats via shfl + 2KB LDS
  const int colq = lane & 15;
  float gc[4], bc[4], wb[4];
#pragma unroll
  for (int n = 0; n < 4; ++n) {
    const int col = wcid * 64 + n * 16 + colq;
    gc[n] = n2g[col]; bc[n] = n2b[col]; wb[n] = doutb[col];
  }
#pragma unroll
  for (int m = 0; m < 4; ++m) {
#pragma unroll
    for (int i = 0; i < 4; ++i) {
      const int row = wr * 64 + m * 16 + ((lane >> 4) << 2) + i;
      const unsigned short* rr = hV1b + (((size_t)(rowbase + row)) << 7) + wcid * 64 + colq;
      float s = 0.f, ss = 0.f;
#pragma unroll
      for (int n = 0; n < 4; ++n) {
        float x = acc2[m][n][i] + wb[n] + bf2f(rr[n * 16]);
        acc2[m][n][i] = x;
        s += x; ss += x * x;
      }
#pragma unroll
      for (int o = 1; o <= 8; o <<= 1) { s += __shfl_xor(s, o); ss += __shfl_xor(ss, o); }
      if (colq == 0) { sStat[row][0][wcid] = s; sStat[row][1][wcid] = ss; }
    }
  }
  __syncthreads();
#pragma unroll
  for (int m = 0; m < 4; ++m) {
#pragma unroll
    for (int i = 0; i < 4; ++i) {
      const int row = wr * 64 + m * 16 + ((lane >> 4) << 2) + i;
      const int grow = rowbase + row;
      const float sum = sStat[row][0][0] + sStat[row][0][1];
      const float ssq = sStat[row][1][0] + sStat[row][1][1];
      const float mean = sum * (1.0f / 128.0f);
      const float inv = rsqrtf(ssq * (1.0f / 128.0f) - mean * mean + EPS_);
      const float mv = maskV[grow];
      float* dst = outV + (((size_t)grow) << 7) + wcid * 64 + colq;
      unsigned short* dstc = hV2c + (((size_t)grow) << 7) + wcid * 64 + colq;
#pragma unroll
      for (int n = 0; n < 4; ++n) {
        const float y = (gc[n] * (acc2[m][n][i] - mean) * inv + bc[n]) * mv;
        dst[n * 16] = y;
        dstc[n * 16] = f2bf(y);
      }
    }
  }
}

// ---- k3: edge message MLP + residual + LN3 -> outE ----
template<bool EBF>
__global__ __launch_bounds__(256, 4) void k3(
    const unsigned short* __restrict__ hV2c, const float* __restrict__ hE,
    const unsigned short* __restrict__ hEb,
    const int* __restrict__ Eidx, const unsigned short* __restrict__ wc,
    const float* __restrict__ W11b, const float* __restrict__ W12b,
    const float* __restrict__ W13b, const float* __restrict__ n3g,
    const float* __restrict__ n3b, float* __restrict__ outE) {
  __shared__ __align__(16) unsigned short sA[128 * LDA];
  __shared__ float sStat[128][2][2];

  const int tid = threadIdx.x;
  const int lane = tid & 63;
  const int w = tid >> 6;
  const int wr = w >> 1, wcid = w & 1;
  const int v0 = blockIdx.x << 2;
  const int b = v0 >> 11;
  const int n0 = v0 & (N_ - 1);
  const int bBase = b * N_;

  const unsigned short* W11c = wc + 81920;
  const unsigned short* W12c = wc + 131072;
  const unsigned short* W13c = wc + 147456;

  f32x4 acc[4][4];
  ZERO_ACC(acc)

  // chunk 0: center hV2 (bf16)
  stage_bf16(sA, tid, [&](int r) {
    const int g = r >> 5;
    return hV2c + (((size_t)(bBase + n0 + g)) << 7);
  });
  __syncthreads();
  wave_gemm<384>(sA, W11c, lane, wr, wcid, acc);
  __syncthreads();

  // chunk 1: gathered hV2 (bf16)
  stage_bf16(sA, tid, [&](int r) {
    const int g = r >> 5;
    int kk = r & 31; if (kk >= K_) kk = K_ - 1;
    const int j = Eidx[(bBase + n0 + g) * K_ + kk];
    return hV2c + (((size_t)(bBase + j)) << 7);
  });
  __syncthreads();
  wave_gemm<384>(sA, W11c + 128, lane, wr, wcid, acc);
  __syncthreads();

  // chunk 2: hE
  if (EBF) {
    stage_bf16(sA, tid, [&](int r) {
      const int g = r >> 5;
      int kk = r & 31; if (kk >= K_) kk = K_ - 1;
      return hEb + (((size_t)((bBase + n0 + g) * K_ + kk)) << 7);
    });
  } else {
    stage_cvt(sA, tid, [&](int r) {
      const int g = r >> 5;
      int kk = r & 31; if (kk >= K_) kk = K_ - 1;
      return hE + (((size_t)((bBase + n0 + g) * K_ + kk)) << 7);
    });
  }
  __syncthreads();
  wave_gemm<384>(sA, W11c + 256, lane, wr, wcid, acc);
  __syncthreads();

  bias_gelu_store(acc, W11b, sA, lane, wr, wcid);
  __syncthreads();

  f32x4 acc2[4][4];
  ZERO_ACC(acc2)
  wave_gemm<128>(sA, W12c, lane, wr, wcid, acc2);
  __syncthreads();
  bias_gelu_store(acc2, W12b, sA, lane, wr, wcid);
  __syncthreads();

  f32x4 acc3[4][4];
  ZERO_ACC(acc3)
  wave_gemm<128>(sA, W13c, lane, wr, wcid, acc3);

  // register epilogue: x = acc3 + bias + hE residual; LN3; store
  const int colq = lane & 15;
  float gc[4], bc[4], wb[4];
#pragma unroll
  for (int n = 0; n < 4; ++n) {
    const int col = wcid * 64 + n * 16 + colq;
    gc[n] = n3g[col]; bc[n] = n3b[col]; wb[n] = W13b[col];
  }
#pragma unroll
  for (int m = 0; m < 4; ++m) {
#pragma unroll
    for (int i = 0; i < 4; ++i) {
      const int row = wr * 64 + m * 16 + ((lane >> 4) << 2) + i;
      const int g = row >> 5, kk = row & 31;
      const bool valid = kk < K_;
      const float* er = hE + (((size_t)((bBase + n0 + g) * K_ + kk)) << 7) + wcid * 64 + colq;
      float s = 0.f, ss = 0.f;
#pragma unroll
      for (int n = 0; n < 4; ++n) {
        float x = acc3[m][n][i] + wb[n];
        if (valid) x += er[n * 16];
        acc3[m][n][i] = x;
        s += x; ss += x * x;
      }
#pragma unroll
      for (int o = 1; o <= 8; o <<= 1) { s += __shfl_xor(s, o); ss += __shfl_xor(ss, o); }
      if (colq == 0) { sStat[row][0][wcid] = s; sStat[row][1][wcid] = ss; }
    }
  }
  __syncthreads();
#pragma unroll
  for (int m = 0; m < 4; ++m) {
#pragma unroll
    for (int i = 0; i < 4; ++i) {
      const int row = wr * 64 + m * 16 + ((lane >> 4) << 2) + i;
      const int g = row >> 5, kk = row & 31;
      if (kk >= K_) continue;
      const float sum = sStat[row][0][0] + sStat[row][0][1];
      const float ssq = sStat[row][1][0] + sStat[row][1][1];
      const float mean = sum * (1.0f / 128.0f);
      const float inv = rsqrtf(ssq * (1.0f / 128.0f) - mean * mean + EPS_);
      float* dst = outE + (((size_t)((bBase + n0 + g) * K_ + kk)) << 7) + wcid * 64 + colq;
#pragma unroll
      for (int n = 0; n < 4; ++n)
        dst[n * 16] = gc[n] * (acc3[m][n][i] - mean) * inv + bc[n];
    }
  }
}

extern "C" void kernel_launch(void* const* d_in, const int* in_sizes, int n_in,
                              void* d_out, int out_size, void* d_ws, size_t ws_size,
                              hipStream_t stream) {
  const float* hV = (const float*)d_in[0];
  const float* hE = (const float*)d_in[1];
  const int* Eidx = (const int*)d_in[2];
  const float* maskV = (const float*)d_in[3];
  const float* mattend = (const float*)d_in[4];
  const float* W1w = (const float*)d_in[5];   const float* W1b = (const float*)d_in[6];
  const float* W2w = (const float*)d_in[7];   const float* W2b = (const float*)d_in[8];
  const float* W3w = (const float*)d_in[9];   const float* W3b = (const float*)d_in[10];
  const float* W11w = (const float*)d_in[11]; const float* W11b = (const float*)d_in[12];
  const float* W12w = (const float*)d_in[13]; const float* W12b = (const float*)d_in[14];
  const float* W13w = (const float*)d_in[15]; const float* W13b = (const float*)d_in[16];
  const float* n1g = (const float*)d_in[17];  const float* n1b = (const float*)d_in[18];
  const float* n2g = (const float*)d_in[19];  const float* n2b = (const float*)d_in[20];
  const float* n3g = (const float*)d_in[21];  const float* n3b = (const float*)d_in[22];
  const float* dinw = (const float*)d_in[23]; const float* dinb = (const float*)d_in[24];
  const float* doutw = (const float*)d_in[25]; const float* doutb = (const float*)d_in[26];

  unsigned short* wc   = (unsigned short*)d_ws;   // 294912 bf16 weights
  unsigned short* hV1b = wc + 294912;             // [B*N*H] bf16 (LN1 out)
  unsigned short* hV2c = hV1b + 2097152;          // [B*N*H] bf16 (LN2 out, masked)
  unsigned short* hVb  = hV2c + 2097152;          // [B*N*H] bf16 (input hV)
  unsigned short* hEb  = hVb + 2097152;           // optional [B*N*K*H] bf16
  // mandatory footprint: 589824 + 3*4194304 = 13,172,736 B (== round-1 proven use)
  const int ebf = ws_size >= 13172736ull + 125829120ull;

  float* outV = (float*)d_out;
  float* outE = outV + (size_t)B_ * N_ * H_;

  prep<<<1152, 256, 0, stream>>>(W1w, W2w, W3w, W11w, W12w, W13w, dinw, doutw, wc);
  cvt8<<<1024, 256, 0, stream>>>(hV, hVb, 262144);
  if (ebf) {
    k1<true><<<4096, 256, 0, stream>>>(hV, hVb, hE, hEb, Eidx, mattend, wc,
                                       W1b, W2b, W3b, n1g, n1b, hV1b);
    k2<<<128, 256, 0, stream>>>(hV1b, wc, dinb, doutb, n2g, n2b, maskV, outV, hV2c);
    k3<true><<<4096, 256, 0, stream>>>(hV2c, hE, hEb, Eidx, wc,
                                       W11b, W12b, W13b, n3g, n3b, outE);
  } else {
    k1<false><<<4096, 256, 0, stream>>>(hV, hVb, hE, hEb, Eidx, mattend, wc,
                                        W1b, W2b, W3b, n1g, n1b, hV1b);
    k2<<<128, 256, 0, stream>>>(hV1b, wc, dinb, doutb, n2g, n2b, maskV, outV, hV2c);
    k3<false><<<4096, 256, 0, stream>>>(hV2c, hE, hEb, Eidx, wc,
                                        W11b, W12b, W13b, n3g, n3b, outE);
  }
}